// Round 1
// baseline (170.455 us; speedup 1.0000x reference)
//
#include <hip/hip_runtime.h>
#include <hip/hip_bf16.h>

// Pinball loss: mean over all elements of max((q-1)*(t-p), q*(t-p)), q = quantiles[0].
// preds, target: [128,512,288] f32 (18,874,368 elems each). Output: 1 f32 scalar.
// Memory-bound streaming reduction: float4 loads, two-stage block reduction via d_ws.

#define BLOCK 256
#define GRID  2048

__global__ __launch_bounds__(BLOCK) void pinball_partial(
    const float* __restrict__ preds,
    const float* __restrict__ target,
    const float* __restrict__ quantiles,
    float* __restrict__ partial,   // [GRID] in d_ws
    int n)                         // total element count
{
    const float q   = quantiles[0];
    const float qm1 = q - 1.0f;

    const int n4     = n >> 2;                         // float4 count
    const int idx    = blockIdx.x * BLOCK + threadIdx.x;
    const int stride = gridDim.x * BLOCK;

    const float4* __restrict__ p4 = (const float4*)preds;
    const float4* __restrict__ t4 = (const float4*)target;

    float acc = 0.0f;
    for (int i = idx; i < n4; i += stride) {
        float4 p = p4[i];
        float4 t = t4[i];
        float e0 = t.x - p.x;
        float e1 = t.y - p.y;
        float e2 = t.z - p.z;
        float e3 = t.w - p.w;
        acc += fmaxf(qm1 * e0, q * e0);
        acc += fmaxf(qm1 * e1, q * e1);
        acc += fmaxf(qm1 * e2, q * e2);
        acc += fmaxf(qm1 * e3, q * e3);
    }
    // scalar tail (n not divisible by 4 — not hit for this shape, but safe)
    for (int i = (n4 << 2) + idx; i < n; i += stride) {
        float e = target[i] - preds[i];
        acc += fmaxf(qm1 * e, q * e);
    }

    // wave64 butterfly reduce
    #pragma unroll
    for (int off = 32; off > 0; off >>= 1)
        acc += __shfl_down(acc, off, 64);

    __shared__ float s[BLOCK / 64];
    const int lane = threadIdx.x & 63;
    const int wid  = threadIdx.x >> 6;
    if (lane == 0) s[wid] = acc;
    __syncthreads();
    if (threadIdx.x == 0) {
        float b = s[0];
        #pragma unroll
        for (int w = 1; w < BLOCK / 64; ++w) b += s[w];
        partial[blockIdx.x] = b;
    }
}

__global__ __launch_bounds__(BLOCK) void pinball_final(
    const float* __restrict__ partial,
    float* __restrict__ out,
    int nblocks,
    float inv_n)
{
    float acc = 0.0f;
    for (int i = threadIdx.x; i < nblocks; i += BLOCK)
        acc += partial[i];

    #pragma unroll
    for (int off = 32; off > 0; off >>= 1)
        acc += __shfl_down(acc, off, 64);

    __shared__ float s[BLOCK / 64];
    const int lane = threadIdx.x & 63;
    const int wid  = threadIdx.x >> 6;
    if (lane == 0) s[wid] = acc;
    __syncthreads();
    if (threadIdx.x == 0) {
        float b = s[0];
        #pragma unroll
        for (int w = 1; w < BLOCK / 64; ++w) b += s[w];
        out[0] = b * inv_n;
    }
}

extern "C" void kernel_launch(void* const* d_in, const int* in_sizes, int n_in,
                              void* d_out, int out_size, void* d_ws, size_t ws_size,
                              hipStream_t stream) {
    const float* preds     = (const float*)d_in[0];
    const float* target    = (const float*)d_in[1];
    const float* quantiles = (const float*)d_in[2];
    float*       out       = (float*)d_out;
    float*       partial   = (float*)d_ws;   // GRID floats — all written before read

    const int n = in_sizes[0];
    const float inv_n = 1.0f / (float)n;

    pinball_partial<<<GRID, BLOCK, 0, stream>>>(preds, target, quantiles, partial, n);
    pinball_final<<<1, BLOCK, 0, stream>>>(partial, out, GRID, inv_n);
}